// Round 2
// baseline (457.079 us; speedup 1.0000x reference)
//
#include <hip/hip_runtime.h>
#include <hip/hip_bf16.h>
#include <stdint.h>

// Problem: out[m,n] = sum_k fp8(inp[m,k]) * fp8(weight[n,k]) + bias[n]
// M=8192, K=4096, N=4096. inp/weight fp32 -> e4m3fn (RNE), fp32 accumulate.

#define MD 8192
#define KD 4096
#define ND 4096
#define BM 128
#define BN 128
#define BK 64

using f32x4 = __attribute__((ext_vector_type(4))) float;

// -------------------------------------------------------------------------
// Quantize fp32 -> fp8 e4m3 (OCP, RNE) -- 8 elements / thread / iter
// -------------------------------------------------------------------------
__global__ __launch_bounds__(256) void quant_fp8_kernel(
    const float* __restrict__ in, uint8_t* __restrict__ out, int n8) {
  int i = blockIdx.x * blockDim.x + threadIdx.x;
  int stride = gridDim.x * blockDim.x;
  for (; i < n8; i += stride) {
    float4 f0 = ((const float4*)in)[2 * i];
    float4 f1 = ((const float4*)in)[2 * i + 1];
    int lo = 0, hi = 0;
    lo = __builtin_amdgcn_cvt_pk_fp8_f32(f0.x, f0.y, lo, false);
    lo = __builtin_amdgcn_cvt_pk_fp8_f32(f0.z, f0.w, lo, true);
    hi = __builtin_amdgcn_cvt_pk_fp8_f32(f1.x, f1.y, hi, false);
    hi = __builtin_amdgcn_cvt_pk_fp8_f32(f1.z, f1.w, hi, true);
    ((int2*)out)[i] = make_int2(lo, hi);
  }
}

// -------------------------------------------------------------------------
// FP8 GEMM (A: MxK fp8 row-major, B: NxK fp8 row-major, C = A*B^T + bias)
// 128x128 tile, BK=64, 4 waves (2x2), mfma_f32_16x16x32_fp8_fp8.
// global_load_lds width=16, linear LDS dest, pre-swizzled global source:
//   LDS 16B-chunk q of row r holds global chunk q ^ ((r>>1)&3)
// -------------------------------------------------------------------------
__device__ __forceinline__ void gload16(const uint8_t* g, uint8_t* l) {
  __builtin_amdgcn_global_load_lds(
      (const __attribute__((address_space(1))) void*)g,
      (__attribute__((address_space(3))) void*)l, 16, 0, 0);
}

__global__ __launch_bounds__(256, 2) void fp8_gemm_bias_kernel(
    const uint8_t* __restrict__ A, const uint8_t* __restrict__ B,
    const __hip_bfloat16* __restrict__ bias, float* __restrict__ C) {
  __shared__ uint8_t sm[2][2][BM * BK];  // [buf][A/B][128 rows x 64B] = 32 KiB

  // XCD-aware bijective swizzle: nwg = 2048, %8 == 0
  const int bid = blockIdx.x;
  const int swz = (bid & 7) * (2048 >> 3) + (bid >> 3);
  const int tm = swz >> 5;   // 0..63   (swz / (N/BN))
  const int tn = swz & 31;   // 0..31

  const int t = threadIdx.x;
  const int w = t >> 6;            // wave 0..3
  const int l = t & 63;
  const int wm = w >> 1, wn = w & 1;
  const int r16 = l & 15, kg = l >> 4;

  // ---- staging addresses (thread t stages 16B; row = t>>2, chunk = t&3) ----
  const int row_a = t >> 2;                       // 0..63
  const int gsw = (t & 3) ^ ((row_a >> 1) & 3);   // pre-swizzled source chunk
  const size_t a0 = (size_t)(tm * BM + row_a) * KD + gsw * 16;
  const size_t a1 = a0 + (size_t)64 * KD;
  const size_t b0 = (size_t)(tn * BN + row_a) * KD + gsw * 16;
  const size_t b1 = b0 + (size_t)64 * KD;
  const int wd = w * 1024;                        // wave-uniform LDS dest

  // ---- fragment read offsets (A frag m, k-chunk kc: 8B per lane) ----
  const int s = (r16 >> 1) & 3;
  const int kg2 = kg >> 1;
  const int sub8 = (kg & 1) * 8;
  const int abase = (wm * 64 + r16) * 64 + sub8;
  const int bbase = (wn * 64 + r16) * 64 + sub8;
  const int ch0 = (kg2 ^ s) * 16;          // kc = 0
  const int ch1 = ((2 | kg2) ^ s) * 16;    // kc = 1

  f32x4 acc[4][4];
#pragma unroll
  for (int m = 0; m < 4; ++m)
#pragma unroll
    for (int n = 0; n < 4; ++n) acc[m][n] = (f32x4){0.f, 0.f, 0.f, 0.f};

  auto stage = [&](int buf, int kt) {
    const size_t ko = (size_t)kt * BK;
    gload16(A + a0 + ko, &sm[buf][0][wd]);
    gload16(A + a1 + ko, &sm[buf][0][4096 + wd]);
    gload16(B + b0 + ko, &sm[buf][1][wd]);
    gload16(B + b1 + ko, &sm[buf][1][4096 + wd]);
  };

  auto compute = [&](int buf) {
    const uint8_t* sa = &sm[buf][0][0];
    const uint8_t* sb = &sm[buf][1][0];
#pragma unroll
    for (int kc = 0; kc < 2; ++kc) {
      const int ch = kc ? ch1 : ch0;
      long long af[4], bf[4];
#pragma unroll
      for (int m = 0; m < 4; ++m)
        af[m] = *(const long long*)(sa + abase + m * 1024 + ch);
#pragma unroll
      for (int n = 0; n < 4; ++n)
        bf[n] = *(const long long*)(sb + bbase + n * 1024 + ch);
#pragma unroll
      for (int m = 0; m < 4; ++m)
#pragma unroll
        for (int n = 0; n < 4; ++n)
          acc[m][n] = __builtin_amdgcn_mfma_f32_16x16x32_fp8_fp8(
              af[m], bf[n], acc[m][n], 0, 0, 0);
    }
  };

  const int NT = KD / BK;  // 64
  stage(0, 0);
  __syncthreads();
#pragma unroll 1
  for (int kt = 0; kt < NT - 1; ++kt) {
    const int cur = kt & 1;
    stage(cur ^ 1, kt + 1);   // issue next-tile loads BEFORE compute
    compute(cur);
    __syncthreads();          // compiler emits vmcnt(0)+lgkmcnt(0) drain here
  }
  compute((NT - 1) & 1);

  // ---- epilogue: C/D layout col = lane&15, row = (lane>>4)*4 + reg ----
  const int gcol = tn * BN + wn * 64 + r16;
  const int grow = tm * BM + wm * 64 + kg * 4;
#pragma unroll
  for (int n = 0; n < 4; ++n) {
    const float bv = __bfloat162float(bias[gcol + n * 16]);
#pragma unroll
    for (int m = 0; m < 4; ++m) {
      const f32x4 v = acc[m][n];
#pragma unroll
      for (int j = 0; j < 4; ++j) {
        C[(size_t)(grow + m * 16 + j) * ND + (gcol + n * 16)] = v[j] + bv;
      }
    }
  }
}

// -------------------------------------------------------------------------
extern "C" void kernel_launch(void* const* d_in, const int* in_sizes, int n_in,
                              void* d_out, int out_size, void* d_ws, size_t ws_size,
                              hipStream_t stream) {
  const float* inp = (const float*)d_in[0];            // (M,K) fp32
  const float* wgt = (const float*)d_in[1];            // (N,K) fp32
  const __hip_bfloat16* bias = (const __hip_bfloat16*)d_in[2];  // (N,) bf16
  float* out = (float*)d_out;                           // (M,N) fp32

  uint8_t* a8 = (uint8_t*)d_ws;                         // M*K fp8 = 32 MiB
  uint8_t* b8 = a8 + (size_t)MD * KD;                   // N*K fp8 = 16 MiB

  quant_fp8_kernel<<<2048, 256, 0, stream>>>(inp, a8, MD * KD / 8);
  quant_fp8_kernel<<<2048, 256, 0, stream>>>(wgt, b8, ND * KD / 8);
  fp8_gemm_bias_kernel<<<2048, 256, 0, stream>>>(a8, b8, bias, out);
}

// Round 3
// 439.144 us; speedup vs baseline: 1.0408x; 1.0408x over previous
//
#include <hip/hip_runtime.h>
#include <hip/hip_bf16.h>
#include <stdint.h>

// Problem: out[m,n] = sum_k fp8(inp[m,k]) * fp8(weight[n,k]) + bias[n]
// M=8192, K=4096, N=4096. inp/weight fp32 -> e4m3fn (RNE), fp32 accumulate.

#define MD 8192
#define KD 4096
#define ND 4096
#define BM 128
#define BN 128
#define BK 64

using f32x4 = __attribute__((ext_vector_type(4))) float;

// -------------------------------------------------------------------------
// Fused quantize fp32 -> fp8 e4m3 for BOTH operands, one launch.
// Contiguous 16B/lane float4 reads (1 KiB/wave), 4B packed stores.
// Two branch-free grid-stride loops (A then W) -> pure streaming.
// -------------------------------------------------------------------------
__global__ __launch_bounds__(256) void quant_fp8_fused_kernel(
    const float* __restrict__ inA, const float* __restrict__ inW,
    uint8_t* __restrict__ outA, uint8_t* __restrict__ outW) {
  const int NA4 = MD * KD / 4;  // 8388608 float4 groups
  const int NW4 = ND * KD / 4;  // 4194304
  const int tid = blockIdx.x * blockDim.x + threadIdx.x;
  const int stride = gridDim.x * blockDim.x;

  for (int i = tid; i < NA4; i += stride) {
    float4 f = ((const float4*)inA)[i];
    int v = 0;
    v = __builtin_amdgcn_cvt_pk_fp8_f32(f.x, f.y, v, false);
    v = __builtin_amdgcn_cvt_pk_fp8_f32(f.z, f.w, v, true);
    ((int*)outA)[i] = v;
  }
  for (int i = tid; i < NW4; i += stride) {
    float4 f = ((const float4*)inW)[i];
    int v = 0;
    v = __builtin_amdgcn_cvt_pk_fp8_f32(f.x, f.y, v, false);
    v = __builtin_amdgcn_cvt_pk_fp8_f32(f.z, f.w, v, true);
    ((int*)outW)[i] = v;
  }
}

// -------------------------------------------------------------------------
// FP8 GEMM (A: MxK fp8 row-major, B: NxK fp8 row-major, C = A*B^T + bias)
// 128x128 tile, BK=64, 4 waves (2x2), mfma_f32_16x16x32_fp8_fp8.
// global_load_lds width=16, linear LDS dest, pre-swizzled global source:
//   LDS 16B-chunk q of row r holds global chunk q ^ ((r>>1)&3)
// UNCHANGED from round 2 (validated anchor: 203 us, MfmaUtil ~60%).
// -------------------------------------------------------------------------
__device__ __forceinline__ void gload16(const uint8_t* g, uint8_t* l) {
  __builtin_amdgcn_global_load_lds(
      (const __attribute__((address_space(1))) void*)g,
      (__attribute__((address_space(3))) void*)l, 16, 0, 0);
}

__global__ __launch_bounds__(256, 2) void fp8_gemm_bias_kernel(
    const uint8_t* __restrict__ A, const uint8_t* __restrict__ B,
    const __hip_bfloat16* __restrict__ bias, float* __restrict__ C) {
  __shared__ uint8_t sm[2][2][BM * BK];  // [buf][A/B][128 rows x 64B] = 32 KiB

  // XCD-aware bijective swizzle: nwg = 2048, %8 == 0
  const int bid = blockIdx.x;
  const int swz = (bid & 7) * (2048 >> 3) + (bid >> 3);
  const int tm = swz >> 5;   // 0..63   (swz / (N/BN))
  const int tn = swz & 31;   // 0..31

  const int t = threadIdx.x;
  const int w = t >> 6;            // wave 0..3
  const int l = t & 63;
  const int wm = w >> 1, wn = w & 1;
  const int r16 = l & 15, kg = l >> 4;

  // ---- staging addresses (thread t stages 16B; row = t>>2, chunk = t&3) ----
  const int row_a = t >> 2;                       // 0..63
  const int gsw = (t & 3) ^ ((row_a >> 1) & 3);   // pre-swizzled source chunk
  const size_t a0 = (size_t)(tm * BM + row_a) * KD + gsw * 16;
  const size_t a1 = a0 + (size_t)64 * KD;
  const size_t b0 = (size_t)(tn * BN + row_a) * KD + gsw * 16;
  const size_t b1 = b0 + (size_t)64 * KD;
  const int wd = w * 1024;                        // wave-uniform LDS dest

  // ---- fragment read offsets (A frag m, k-chunk kc: 8B per lane) ----
  const int s = (r16 >> 1) & 3;
  const int kg2 = kg >> 1;
  const int sub8 = (kg & 1) * 8;
  const int abase = (wm * 64 + r16) * 64 + sub8;
  const int bbase = (wn * 64 + r16) * 64 + sub8;
  const int ch0 = (kg2 ^ s) * 16;          // kc = 0
  const int ch1 = ((2 | kg2) ^ s) * 16;    // kc = 1

  f32x4 acc[4][4];
#pragma unroll
  for (int m = 0; m < 4; ++m)
#pragma unroll
    for (int n = 0; n < 4; ++n) acc[m][n] = (f32x4){0.f, 0.f, 0.f, 0.f};

  auto stage = [&](int buf, int kt) {
    const size_t ko = (size_t)kt * BK;
    gload16(A + a0 + ko, &sm[buf][0][wd]);
    gload16(A + a1 + ko, &sm[buf][0][4096 + wd]);
    gload16(B + b0 + ko, &sm[buf][1][wd]);
    gload16(B + b1 + ko, &sm[buf][1][4096 + wd]);
  };

  auto compute = [&](int buf) {
    const uint8_t* sa = &sm[buf][0][0];
    const uint8_t* sb = &sm[buf][1][0];
#pragma unroll
    for (int kc = 0; kc < 2; ++kc) {
      const int ch = kc ? ch1 : ch0;
      long long af[4], bf[4];
#pragma unroll
      for (int m = 0; m < 4; ++m)
        af[m] = *(const long long*)(sa + abase + m * 1024 + ch);
#pragma unroll
      for (int n = 0; n < 4; ++n)
        bf[n] = *(const long long*)(sb + bbase + n * 1024 + ch);
#pragma unroll
      for (int m = 0; m < 4; ++m)
#pragma unroll
        for (int n = 0; n < 4; ++n)
          acc[m][n] = __builtin_amdgcn_mfma_f32_16x16x32_fp8_fp8(
              af[m], bf[n], acc[m][n], 0, 0, 0);
    }
  };

  const int NT = KD / BK;  // 64
  stage(0, 0);
  __syncthreads();
#pragma unroll 1
  for (int kt = 0; kt < NT - 1; ++kt) {
    const int cur = kt & 1;
    stage(cur ^ 1, kt + 1);   // issue next-tile loads BEFORE compute
    compute(cur);
    __syncthreads();          // compiler emits vmcnt(0)+lgkmcnt(0) drain here
  }
  compute((NT - 1) & 1);

  // ---- epilogue: C/D layout col = lane&15, row = (lane>>4)*4 + reg ----
  const int gcol = tn * BN + wn * 64 + r16;
  const int grow = tm * BM + wm * 64 + kg * 4;
#pragma unroll
  for (int n = 0; n < 4; ++n) {
    const float bv = __bfloat162float(bias[gcol + n * 16]);
#pragma unroll
    for (int m = 0; m < 4; ++m) {
      const f32x4 v = acc[m][n];
#pragma unroll
      for (int j = 0; j < 4; ++j) {
        C[(size_t)(grow + m * 16 + j) * ND + (gcol + n * 16)] = v[j] + bv;
      }
    }
  }
}

// -------------------------------------------------------------------------
extern "C" void kernel_launch(void* const* d_in, const int* in_sizes, int n_in,
                              void* d_out, int out_size, void* d_ws, size_t ws_size,
                              hipStream_t stream) {
  const float* inp = (const float*)d_in[0];            // (M,K) fp32
  const float* wgt = (const float*)d_in[1];            // (N,K) fp32
  const __hip_bfloat16* bias = (const __hip_bfloat16*)d_in[2];  // (N,) bf16
  float* out = (float*)d_out;                           // (M,N) fp32

  uint8_t* a8 = (uint8_t*)d_ws;                         // M*K fp8 = 32 MiB
  uint8_t* b8 = a8 + (size_t)MD * KD;                   // N*K fp8 = 16 MiB

  quant_fp8_fused_kernel<<<2048, 256, 0, stream>>>(inp, wgt, a8, b8);
  fp8_gemm_bias_kernel<<<2048, 256, 0, stream>>>(a8, b8, bias, out);
}

// Round 6
// 418.247 us; speedup vs baseline: 1.0928x; 1.0500x over previous
//
#include <hip/hip_runtime.h>
#include <hip/hip_bf16.h>
#include <stdint.h>

// Problem: out[m,n] = sum_k fp8(inp[m,k]) * fp8(weight[n,k]) + bias[n]
// M=8192, K=4096, N=4096. inp/weight fp32 -> e4m3fn (RNE), fp32 accumulate.
//
// Round 5 (resubmit #2; container failure): GEMM on MX-scaled
// mfma_scale_f32_32x32x64_f8f6f4 with unit scales (E8M0 0x7F = 2^0)
// -> 2.3x MFMA-rate ceiling vs non-scaled fp8.
// Plus 4x4 grouped rasterization inside each XCD chunk (L2 working set 4MB).

#define MD 8192
#define KD 4096
#define ND 4096
#define BM 128
#define BN 128
#define BK 64

using f32x4  = __attribute__((ext_vector_type(4))) float;
using f32x16 = __attribute__((ext_vector_type(16))) float;
using i32x4  = __attribute__((ext_vector_type(4))) int;
using i32x8  = __attribute__((ext_vector_type(8))) int;

// -------------------------------------------------------------------------
// Fused quantize fp32 -> fp8 e4m3 (validated round 3; unchanged)
// -------------------------------------------------------------------------
__global__ __launch_bounds__(256) void quant_fp8_fused_kernel(
    const float* __restrict__ inA, const float* __restrict__ inW,
    uint8_t* __restrict__ outA, uint8_t* __restrict__ outW) {
  const int NA4 = MD * KD / 4;
  const int NW4 = ND * KD / 4;
  const int tid = blockIdx.x * blockDim.x + threadIdx.x;
  const int stride = gridDim.x * blockDim.x;

  for (int i = tid; i < NA4; i += stride) {
    float4 f = ((const float4*)inA)[i];
    int v = 0;
    v = __builtin_amdgcn_cvt_pk_fp8_f32(f.x, f.y, v, false);
    v = __builtin_amdgcn_cvt_pk_fp8_f32(f.z, f.w, v, true);
    ((int*)outA)[i] = v;
  }
  for (int i = tid; i < NW4; i += stride) {
    float4 f = ((const float4*)inW)[i];
    int v = 0;
    v = __builtin_amdgcn_cvt_pk_fp8_f32(f.x, f.y, v, false);
    v = __builtin_amdgcn_cvt_pk_fp8_f32(f.z, f.w, v, true);
    ((int*)outW)[i] = v;
  }
}

// -------------------------------------------------------------------------
// MX-FP8 GEMM (A: MxK, B: NxK, C = A*B^T + bias), unit block scales.
// 128x128 tile, BK=64, 4 waves (2x2), each wave 64x64 = 2x2 frags of 32x32.
// Staging unchanged (validated): global_load_lds width=16, linear LDS dest,
// pre-swizzled source; LDS chunk c of row r holds global chunk c ^ ((r>>1)&3).
// -------------------------------------------------------------------------
__device__ __forceinline__ void gload16(const uint8_t* g, uint8_t* l) {
  __builtin_amdgcn_global_load_lds(
      (const __attribute__((address_space(1))) void*)g,
      (__attribute__((address_space(3))) void*)l, 16, 0, 0);
}

__global__ __launch_bounds__(256, 2) void fp8mx_gemm_bias_kernel(
    const uint8_t* __restrict__ A, const uint8_t* __restrict__ B,
    const __hip_bfloat16* __restrict__ bias, float* __restrict__ C) {
  __shared__ uint8_t sm[2][2][BM * BK];  // 32 KiB

  // ---- rasterization: XCD chunk (bijective, 2048%8==0) + 4x4 groups ----
  // Each XCD chunk = 256 blocks covering tm in [8c,8c+8) x tn in [0,32).
  // Within chunk: 16 groups of 4x4 tiles -> L2 working set 4+4 panels = 4MB.
  const int bid = blockIdx.x;
  const int chunk = bid & 7;         // XCD
  const int local = bid >> 3;        // 0..255 within chunk
  const int g = local >> 4, li = local & 15;
  const int tm = chunk * 8 + (g >> 3) * 4 + (li >> 2);  // 0..63
  const int tn = (g & 7) * 4 + (li & 3);                // 0..31

  const int t = threadIdx.x;
  const int w = t >> 6;              // wave 0..3
  const int l = t & 63;
  const int wm = w >> 1, wn = w & 1;
  const int r31 = l & 31, kh = l >> 5;

  // ---- staging addresses (thread t stages 16B; row = t>>2, chunk = t&3) ----
  const int row_a = t >> 2;                       // 0..63
  const int gsw = (t & 3) ^ ((row_a >> 1) & 3);   // pre-swizzled source chunk
  const size_t a0 = (size_t)(tm * BM + row_a) * KD + gsw * 16;
  const size_t a1 = a0 + (size_t)64 * KD;
  const size_t b0 = (size_t)(tn * BN + row_a) * KD + gsw * 16;
  const size_t b1 = b0 + (size_t)64 * KD;
  const int wd = w * 1024;                        // wave-uniform LDS dest

  // ---- fragment read offsets: lane needs global k-chunks {2kh, 2kh+1} ----
  // (row base wm*64+f*32 is a multiple of 32 -> contributes 0 to (row>>1)&3)
  const int s = (r31 >> 1) & 3;
  const int cLo = (((kh << 1) | 0) ^ s) * 16;
  const int cHi = (((kh << 1) | 1) ^ s) * 16;

  f32x16 acc[2][2];
#pragma unroll
  for (int fm = 0; fm < 2; ++fm)
#pragma unroll
    for (int fn = 0; fn < 2; ++fn)
#pragma unroll
      for (int r = 0; r < 16; ++r) acc[fm][fn][r] = 0.f;

  auto stage = [&](int buf, int kt) {
    const size_t ko = (size_t)kt * BK;
    gload16(A + a0 + ko, &sm[buf][0][wd]);
    gload16(A + a1 + ko, &sm[buf][0][4096 + wd]);
    gload16(B + b0 + ko, &sm[buf][1][wd]);
    gload16(B + b1 + ko, &sm[buf][1][4096 + wd]);
  };

  auto compute = [&](int buf) {
    const uint8_t* sa = &sm[buf][0][0];
    const uint8_t* sb = &sm[buf][1][0];
    i32x8 af[2], bf[2];
#pragma unroll
    for (int f = 0; f < 2; ++f) {
      const int ra = (wm * 64 + f * 32 + r31) * 64;
      i32x4 alo = *(const i32x4*)(sa + ra + cLo);
      i32x4 ahi = *(const i32x4*)(sa + ra + cHi);
      const int rb = (wn * 64 + f * 32 + r31) * 64;
      i32x4 blo = *(const i32x4*)(sb + rb + cLo);
      i32x4 bhi = *(const i32x4*)(sb + rb + cHi);
#pragma unroll
      for (int j = 0; j < 4; ++j) {
        af[f][j] = alo[j]; af[f][4 + j] = ahi[j];
        bf[f][j] = blo[j]; bf[f][4 + j] = bhi[j];
      }
    }
#pragma unroll
    for (int fm = 0; fm < 2; ++fm)
#pragma unroll
      for (int fn = 0; fn < 2; ++fn)
        acc[fm][fn] = __builtin_amdgcn_mfma_scale_f32_32x32x64_f8f6f4(
            af[fm], bf[fn], acc[fm][fn],
            0, 0,                    // cbsz = fp8 e4m3, blgp = fp8 e4m3
            0, 0x7F7F7F7F,           // scale_a opsel, E8M0 unit scales
            0, 0x7F7F7F7F);          // scale_b opsel, E8M0 unit scales
  };

  const int NT = KD / BK;  // 64
  stage(0, 0);
  __syncthreads();
#pragma unroll 1
  for (int kt = 0; kt < NT - 1; ++kt) {
    const int cur = kt & 1;
    stage(cur ^ 1, kt + 1);   // issue next-tile loads BEFORE compute
    compute(cur);
    __syncthreads();          // compiler emits vmcnt(0)+lgkmcnt(0) drain here
  }
  compute((NT - 1) & 1);

  // ---- epilogue: 32x32 C/D layout (HW-verified, shape-determined):
  //      col = lane&31, row = (reg&3) + 8*(reg>>2) + 4*(lane>>5) ----
#pragma unroll
  for (int fm = 0; fm < 2; ++fm)
#pragma unroll
    for (int fn = 0; fn < 2; ++fn) {
      const int col = tn * BN + wn * 64 + fn * 32 + r31;
      const float bv = __bfloat162float(bias[col]);
      const int row0 = tm * BM + wm * 64 + fm * 32 + 4 * kh;
      const f32x16 v = acc[fm][fn];
#pragma unroll
      for (int r = 0; r < 16; ++r) {
        const int row = row0 + (r & 3) + 8 * (r >> 2);
        C[(size_t)row * ND + col] = v[r] + bv;
      }
    }
}

// -------------------------------------------------------------------------
extern "C" void kernel_launch(void* const* d_in, const int* in_sizes, int n_in,
                              void* d_out, int out_size, void* d_ws, size_t ws_size,
                              hipStream_t stream) {
  const float* inp = (const float*)d_in[0];            // (M,K) fp32
  const float* wgt = (const float*)d_in[1];            // (N,K) fp32
  const __hip_bfloat16* bias = (const __hip_bfloat16*)d_in[2];  // (N,) bf16
  float* out = (float*)d_out;                           // (M,N) fp32

  uint8_t* a8 = (uint8_t*)d_ws;                         // M*K fp8 = 32 MiB
  uint8_t* b8 = a8 + (size_t)MD * KD;                   // N*K fp8 = 16 MiB

  quant_fp8_fused_kernel<<<2048, 256, 0, stream>>>(inp, wgt, a8, b8);
  fp8mx_gemm_bias_kernel<<<2048, 256, 0, stream>>>(a8, b8, bias, out);
}

// Round 7
// 399.658 us; speedup vs baseline: 1.1437x; 1.0465x over previous
//
#include <hip/hip_runtime.h>
#include <hip/hip_bf16.h>
#include <stdint.h>

// Problem: out[m,n] = sum_k fp8(inp[m,k]) * fp8(weight[n,k]) + bias[n]
// M=8192, K=4096, N=4096. inp/weight fp32 -> e4m3fn (RNE), fp32 accumulate.
//
// Round 7: fat wave tiles. Block 256x128, 4 waves of 128x64 (4x2 frags of
// 32x32x64 MX-scaled MFMA, unit scales). 1.5 ds_read_b128 per MFMA (was 2.0),
// 2x FLOP per barrier. Staging/sync skeleton unchanged (validated r6).
// Quant: 16B int4 stores (was 4B).

#define MD 8192
#define KD 4096
#define ND 4096
#define BM 256
#define BN 128
#define BK 64

using f32x16 = __attribute__((ext_vector_type(16))) float;
using i32x4  = __attribute__((ext_vector_type(4))) int;
using i32x8  = __attribute__((ext_vector_type(8))) int;

// -------------------------------------------------------------------------
// Fused quantize fp32 -> fp8 e4m3. 16 floats/thread/iter -> one int4 store
// (fully coalesced 1KiB/wave stores; reads hit L1 across the 4 sub-loads).
// -------------------------------------------------------------------------
__device__ __forceinline__ int q4(float4 f) {
  int v = 0;
  v = __builtin_amdgcn_cvt_pk_fp8_f32(f.x, f.y, v, false);
  v = __builtin_amdgcn_cvt_pk_fp8_f32(f.z, f.w, v, true);
  return v;
}

__global__ __launch_bounds__(256) void quant_fp8_fused_kernel(
    const float* __restrict__ inA, const float* __restrict__ inW,
    uint8_t* __restrict__ outA, uint8_t* __restrict__ outW) {
  const int NA16 = MD * KD / 16;   // 2097152
  const int NW16 = ND * KD / 16;   // 1048576
  const int tid = blockIdx.x * blockDim.x + threadIdx.x;
  const int stride = gridDim.x * blockDim.x;  // 524288 -> 4 + 2 iters exactly

  for (int i = tid; i < NA16; i += stride) {
    const float4* p = (const float4*)inA + (size_t)i * 4;
    int4 v = make_int4(q4(p[0]), q4(p[1]), q4(p[2]), q4(p[3]));
    ((int4*)outA)[i] = v;
  }
  for (int i = tid; i < NW16; i += stride) {
    const float4* p = (const float4*)inW + (size_t)i * 4;
    int4 v = make_int4(q4(p[0]), q4(p[1]), q4(p[2]), q4(p[3]));
    ((int4*)outW)[i] = v;
  }
}

// -------------------------------------------------------------------------
// MX-FP8 GEMM (A: MxK, B: NxK, C = A*B^T + bias), unit block scales.
// Block 256x128, BK=64, 4 waves (2x2), wave = 128x64 = 4x2 frags of 32x32.
// Staging: global_load_lds width=16, linear LDS dest, pre-swizzled source;
// LDS chunk c of row r holds global chunk c ^ ((r>>1)&3).
// -------------------------------------------------------------------------
__device__ __forceinline__ void gload16(const uint8_t* g, uint8_t* l) {
  __builtin_amdgcn_global_load_lds(
      (const __attribute__((address_space(1))) void*)g,
      (__attribute__((address_space(3))) void*)l, 16, 0, 0);
}

__global__ __launch_bounds__(256, 2) void fp8mx_gemm_bias_kernel(
    const uint8_t* __restrict__ A, const uint8_t* __restrict__ B,
    const __hip_bfloat16* __restrict__ bias, float* __restrict__ C) {
  // A: 256x64 = 16KiB, B: 128x64 = 8KiB, double-buffered = 48 KiB
  __shared__ uint8_t sm[2][24576];

  // ---- rasterization: 1024 blocks, XCD chunk (1024%8==0) + 2x4 groups ----
  // Per XCD: tm in [xcd*4, xcd*4+4) x tn in [0,32). Groups of 2tm x 4tn:
  // working set 2x1MB (A) + 4x0.5MB (B) = 4MB = XCD L2.
  const int bid = blockIdx.x;
  const int xcd = bid & 7;
  const int local = bid >> 3;          // 0..127
  const int grp = local >> 3, li = local & 7;
  const int tm = xcd * 4 + (grp >> 3) * 2 + (li >> 2);  // 0..31
  const int tn = (grp & 7) * 4 + (li & 3);              // 0..31

  const int t = threadIdx.x;
  const int w = t >> 6;                // wave 0..3
  const int l = t & 63;
  const int wm = w >> 1, wn = w & 1;
  const int r31 = l & 31, kh = l >> 5;

  // ---- staging addresses (thread t stages 16B; row = t>>2, chunk = t&3) ----
  const int row_s = t >> 2;                       // 0..63
  const int gsw = (t & 3) ^ ((row_s >> 1) & 3);   // pre-swizzled source chunk
  const size_t abase = (size_t)(tm * BM + row_s) * KD + gsw * 16;
  const size_t bbase = (size_t)(tn * BN + row_s) * KD + gsw * 16;
  const int wd = w * 1024;                        // wave-uniform LDS dest

  // ---- fragment read chunk offsets: lane needs k-chunks {2kh, 2kh+1} ----
  // (row bases are multiples of 32 -> contribute 0 to (row>>1)&3)
  const int s = (r31 >> 1) & 3;
  const int cLo = (((kh << 1) | 0) ^ s) * 16;
  const int cHi = (((kh << 1) | 1) ^ s) * 16;

  f32x16 acc[4][2];
#pragma unroll
  for (int fm = 0; fm < 4; ++fm)
#pragma unroll
    for (int fn = 0; fn < 2; ++fn)
#pragma unroll
      for (int r = 0; r < 16; ++r) acc[fm][fn][r] = 0.f;

  auto stage = [&](int buf, int kt) {
    const size_t ko = (size_t)kt * BK;
    uint8_t* la = &sm[buf][wd];
#pragma unroll
    for (int rnd = 0; rnd < 4; ++rnd)  // A: rows rnd*64 + row_s
      gload16(A + abase + (size_t)rnd * 64 * KD + ko, la + rnd * 4096);
    uint8_t* lb = &sm[buf][16384 + wd];
#pragma unroll
    for (int rnd = 0; rnd < 2; ++rnd)  // B: rows rnd*64 + row_s
      gload16(B + bbase + (size_t)rnd * 64 * KD + ko, lb + rnd * 4096);
  };

  auto compute = [&](int buf) {
    const uint8_t* sa = &sm[buf][0];
    const uint8_t* sb = &sm[buf][16384];
    i32x8 af[4], bf[2];
#pragma unroll
    for (int fm = 0; fm < 4; ++fm) {
      const int ra = (wm * 128 + fm * 32 + r31) * 64;
      i32x4 lo = *(const i32x4*)(sa + ra + cLo);
      i32x4 hi = *(const i32x4*)(sa + ra + cHi);
#pragma unroll
      for (int j = 0; j < 4; ++j) { af[fm][j] = lo[j]; af[fm][4 + j] = hi[j]; }
    }
#pragma unroll
    for (int fn = 0; fn < 2; ++fn) {
      const int rb = (wn * 64 + fn * 32 + r31) * 64;
      i32x4 lo = *(const i32x4*)(sb + rb + cLo);
      i32x4 hi = *(const i32x4*)(sb + rb + cHi);
#pragma unroll
      for (int j = 0; j < 4; ++j) { bf[fn][j] = lo[j]; bf[fn][4 + j] = hi[j]; }
    }
#pragma unroll
    for (int fm = 0; fm < 4; ++fm)
#pragma unroll
      for (int fn = 0; fn < 2; ++fn)
        acc[fm][fn] = __builtin_amdgcn_mfma_scale_f32_32x32x64_f8f6f4(
            af[fm], bf[fn], acc[fm][fn],
            0, 0,                    // cbsz = fp8 e4m3, blgp = fp8 e4m3
            0, 0x7F7F7F7F,           // scale_a opsel, E8M0 unit scales
            0, 0x7F7F7F7F);          // scale_b opsel, E8M0 unit scales
  };

  const int NT = KD / BK;  // 64
  stage(0, 0);
  __syncthreads();
#pragma unroll 1
  for (int kt = 0; kt < NT - 1; ++kt) {
    const int cur = kt & 1;
    stage(cur ^ 1, kt + 1);   // issue next-tile loads BEFORE compute
    compute(cur);
    __syncthreads();          // compiler emits vmcnt(0)+lgkmcnt(0) drain here
  }
  compute((NT - 1) & 1);

  // ---- epilogue: 32x32 C/D layout (HW-verified, shape-determined):
  //      col = lane&31, row = (reg&3) + 8*(reg>>2) + 4*(lane>>5) ----
#pragma unroll
  for (int fn = 0; fn < 2; ++fn) {
    const int col = tn * BN + wn * 64 + fn * 32 + r31;
    const float bv = __bfloat162float(bias[col]);
#pragma unroll
    for (int fm = 0; fm < 4; ++fm) {
      const int row0 = tm * BM + wm * 128 + fm * 32 + 4 * kh;
      const f32x16 v = acc[fm][fn];
#pragma unroll
      for (int r = 0; r < 16; ++r) {
        const int row = row0 + (r & 3) + 8 * (r >> 2);
        C[(size_t)row * ND + col] = v[r] + bv;
      }
    }
  }
}

// -------------------------------------------------------------------------
extern "C" void kernel_launch(void* const* d_in, const int* in_sizes, int n_in,
                              void* d_out, int out_size, void* d_ws, size_t ws_size,
                              hipStream_t stream) {
  const float* inp = (const float*)d_in[0];            // (M,K) fp32
  const float* wgt = (const float*)d_in[1];            // (N,K) fp32
  const __hip_bfloat16* bias = (const __hip_bfloat16*)d_in[2];  // (N,) bf16
  float* out = (float*)d_out;                           // (M,N) fp32

  uint8_t* a8 = (uint8_t*)d_ws;                         // M*K fp8 = 32 MiB
  uint8_t* b8 = a8 + (size_t)MD * KD;                   // N*K fp8 = 16 MiB

  quant_fp8_fused_kernel<<<2048, 256, 0, stream>>>(inp, wgt, a8, b8);
  fp8mx_gemm_bias_kernel<<<1024, 256, 0, stream>>>(a8, b8, bias, out);
}

// Round 8
// 395.162 us; speedup vs baseline: 1.1567x; 1.0114x over previous
//
#include <hip/hip_runtime.h>
#include <hip/hip_bf16.h>
#include <stdint.h>

// Problem: out[m,n] = sum_k fp8(inp[m,k]) * fp8(weight[n,k]) + bias[n]
// M=8192, K=4096, N=4096. inp/weight fp32 -> e4m3fn (RNE), fp32 accumulate.
//
// Round 8: counted-vmcnt depth-2 pipeline (T4). Geometry unchanged from r7
// (block 256x128, 4 waves of 128x64, MX-scaled 32x32x64 MFMA, unit scales).
// 3 LDS buffers; per iter: vmcnt(6) waits ONLY the oldest tile's loads
// (issued 2 iters earlier), newer 6 stay in flight across a raw s_barrier.

#define MD 8192
#define KD 4096
#define ND 4096
#define BM 256
#define BN 128
#define BK 64

using f32x16 = __attribute__((ext_vector_type(16))) float;
using i32x4  = __attribute__((ext_vector_type(4))) int;
using i32x8  = __attribute__((ext_vector_type(8))) int;

// -------------------------------------------------------------------------
// Fused quantize fp32 -> fp8 e4m3 (validated r7; unchanged)
// -------------------------------------------------------------------------
__device__ __forceinline__ int q4(float4 f) {
  int v = 0;
  v = __builtin_amdgcn_cvt_pk_fp8_f32(f.x, f.y, v, false);
  v = __builtin_amdgcn_cvt_pk_fp8_f32(f.z, f.w, v, true);
  return v;
}

__global__ __launch_bounds__(256) void quant_fp8_fused_kernel(
    const float* __restrict__ inA, const float* __restrict__ inW,
    uint8_t* __restrict__ outA, uint8_t* __restrict__ outW) {
  const int NA16 = MD * KD / 16;
  const int NW16 = ND * KD / 16;
  const int tid = blockIdx.x * blockDim.x + threadIdx.x;
  const int stride = gridDim.x * blockDim.x;

  for (int i = tid; i < NA16; i += stride) {
    const float4* p = (const float4*)inA + (size_t)i * 4;
    int4 v = make_int4(q4(p[0]), q4(p[1]), q4(p[2]), q4(p[3]));
    ((int4*)outA)[i] = v;
  }
  for (int i = tid; i < NW16; i += stride) {
    const float4* p = (const float4*)inW + (size_t)i * 4;
    int4 v = make_int4(q4(p[0]), q4(p[1]), q4(p[2]), q4(p[3]));
    ((int4*)outW)[i] = v;
  }
}

// -------------------------------------------------------------------------
// MX-FP8 GEMM (A: MxK, B: NxK, C = A*B^T + bias), unit block scales.
// Block 256x128, BK=64, 4 waves (2x2), wave = 128x64 = 4x2 frags of 32x32.
// Staging: global_load_lds width=16, linear LDS dest, pre-swizzled source;
// LDS chunk c of row r holds global chunk c ^ ((r>>1)&3).
// -------------------------------------------------------------------------
__device__ __forceinline__ void gload16(const uint8_t* g, uint8_t* l) {
  __builtin_amdgcn_global_load_lds(
      (const __attribute__((address_space(1))) void*)g,
      (__attribute__((address_space(3))) void*)l, 16, 0, 0);
}

__global__ __launch_bounds__(256, 2) void fp8mx_gemm_bias_kernel(
    const uint8_t* __restrict__ A, const uint8_t* __restrict__ B,
    const __hip_bfloat16* __restrict__ bias, float* __restrict__ C) {
  // A: 256x64 = 16KiB + B: 128x64 = 8KiB per tile; 3 buffers = 72 KiB
  __shared__ uint8_t sm[3][24576];

  // ---- rasterization: 1024 blocks, XCD chunk (1024%8==0) + 2x4 groups ----
  const int bid = blockIdx.x;
  const int xcd = bid & 7;
  const int local = bid >> 3;          // 0..127
  const int grp = local >> 3, li = local & 7;
  const int tm = xcd * 4 + (grp >> 3) * 2 + (li >> 2);  // 0..31
  const int tn = (grp & 7) * 4 + (li & 3);              // 0..31

  const int t = threadIdx.x;
  const int w = t >> 6;                // wave 0..3
  const int l = t & 63;
  const int wm = w >> 1, wn = w & 1;
  const int r31 = l & 31, kh = l >> 5;

  // ---- staging addresses (thread t stages 16B; row = t>>2, chunk = t&3) ----
  const int row_s = t >> 2;                       // 0..63
  const int gsw = (t & 3) ^ ((row_s >> 1) & 3);   // pre-swizzled source chunk
  const size_t abase = (size_t)(tm * BM + row_s) * KD + gsw * 16;
  const size_t bbase = (size_t)(tn * BN + row_s) * KD + gsw * 16;
  const int wd = w * 1024;                        // wave-uniform LDS dest

  // ---- fragment read chunk offsets: lane needs k-chunks {2kh, 2kh+1} ----
  const int s = (r31 >> 1) & 3;
  const int cLo = (((kh << 1) | 0) ^ s) * 16;
  const int cHi = (((kh << 1) | 1) ^ s) * 16;

  f32x16 acc[4][2];
#pragma unroll
  for (int fm = 0; fm < 4; ++fm)
#pragma unroll
    for (int fn = 0; fn < 2; ++fn)
#pragma unroll
      for (int r = 0; r < 16; ++r) acc[fm][fn][r] = 0.f;

  auto stage = [&](int buf, int kt) {
    const size_t ko = (size_t)kt * BK;
    uint8_t* la = &sm[buf][wd];
#pragma unroll
    for (int rnd = 0; rnd < 4; ++rnd)  // A rows rnd*64 + row_s
      gload16(A + abase + (size_t)rnd * 64 * KD + ko, la + rnd * 4096);
    uint8_t* lb = &sm[buf][16384 + wd];
#pragma unroll
    for (int rnd = 0; rnd < 2; ++rnd)  // B rows rnd*64 + row_s
      gload16(B + bbase + (size_t)rnd * 64 * KD + ko, lb + rnd * 4096);
  };

  auto compute = [&](int buf) {
    const uint8_t* sa = &sm[buf][0];
    const uint8_t* sb = &sm[buf][16384];
    i32x8 af[4], bf[2];
#pragma unroll
    for (int fm = 0; fm < 4; ++fm) {
      const int ra = (wm * 128 + fm * 32 + r31) * 64;
      i32x4 lo = *(const i32x4*)(sa + ra + cLo);
      i32x4 hi = *(const i32x4*)(sa + ra + cHi);
#pragma unroll
      for (int j = 0; j < 4; ++j) { af[fm][j] = lo[j]; af[fm][4 + j] = hi[j]; }
    }
#pragma unroll
    for (int fn = 0; fn < 2; ++fn) {
      const int rb = (wn * 64 + fn * 32 + r31) * 64;
      i32x4 lo = *(const i32x4*)(sb + rb + cLo);
      i32x4 hi = *(const i32x4*)(sb + rb + cHi);
#pragma unroll
      for (int j = 0; j < 4; ++j) { bf[fn][j] = lo[j]; bf[fn][4 + j] = hi[j]; }
    }
#pragma unroll
    for (int fm = 0; fm < 4; ++fm)
#pragma unroll
      for (int fn = 0; fn < 2; ++fn)
        acc[fm][fn] = __builtin_amdgcn_mfma_scale_f32_32x32x64_f8f6f4(
            af[fm], bf[fn], acc[fm][fn],
            0, 0,                    // cbsz = fp8 e4m3, blgp = fp8 e4m3
            0, 0x7F7F7F7F,           // scale_a opsel, E8M0 unit scales
            0, 0x7F7F7F7F);          // scale_b opsel, E8M0 unit scales
  };

  // ---- depth-2 counted-vmcnt pipeline ----
  // Invariants at top of iter kt: tiles kt (oldest, 6 loads) and kt+1
  // (6 loads) outstanding. vmcnt(6) retires tile kt only; barrier makes it
  // collective. stage(kt+2) targets buf (kt-1)%3 whose readers all passed
  // the PREVIOUS barrier (compute(kt-1) precedes it in program order).
  const int NT = KD / BK;  // 64
  stage(0, 0);
  stage(1, 1);
#pragma unroll 1
  for (int kt = 0; kt < NT - 1; ++kt) {
    asm volatile("s_waitcnt vmcnt(6)" ::: "memory");
    __builtin_amdgcn_s_barrier();
    if (kt + 2 < NT) stage((kt + 2) % 3, kt + 2);
    compute(kt % 3);
  }
  asm volatile("s_waitcnt vmcnt(0)" ::: "memory");
  __builtin_amdgcn_s_barrier();
  compute((NT - 1) % 3);

  // ---- epilogue: 32x32 C/D layout:
  //      col = lane&31, row = (reg&3) + 8*(reg>>2) + 4*(lane>>5) ----
#pragma unroll
  for (int fn = 0; fn < 2; ++fn) {
    const int col = tn * BN + wn * 64 + fn * 32 + r31;
    const float bv = __bfloat162float(bias[col]);
#pragma unroll
    for (int fm = 0; fm < 4; ++fm) {
      const int row0 = tm * BM + wm * 128 + fm * 32 + 4 * kh;
      const f32x16 v = acc[fm][fn];
#pragma unroll
      for (int r = 0; r < 16; ++r) {
        const int row = row0 + (r & 3) + 8 * (r >> 2);
        C[(size_t)row * ND + col] = v[r] + bv;
      }
    }
  }
}

// -------------------------------------------------------------------------
extern "C" void kernel_launch(void* const* d_in, const int* in_sizes, int n_in,
                              void* d_out, int out_size, void* d_ws, size_t ws_size,
                              hipStream_t stream) {
  const float* inp = (const float*)d_in[0];            // (M,K) fp32
  const float* wgt = (const float*)d_in[1];            // (N,K) fp32
  const __hip_bfloat16* bias = (const __hip_bfloat16*)d_in[2];  // (N,) bf16
  float* out = (float*)d_out;                           // (M,N) fp32

  uint8_t* a8 = (uint8_t*)d_ws;                         // M*K fp8 = 32 MiB
  uint8_t* b8 = a8 + (size_t)MD * KD;                   // N*K fp8 = 16 MiB

  quant_fp8_fused_kernel<<<2048, 256, 0, stream>>>(inp, wgt, a8, b8);
  fp8mx_gemm_bias_kernel<<<1024, 256, 0, stream>>>(a8, b8, bias, out);
}